// Round 1
// baseline (41.446 us; speedup 1.0000x reference)
//
#include <hip/hip_runtime.h>

#define NB 8
#define NT 2048
#define ND 1024
#define NS 512
#define NW 16

// One block per (b, s) span. 256 threads; thread t owns d = 4t .. 4t+3.
__global__ __launch_bounds__(256) void span_attn_kernel(
    const float* __restrict__ text,   // [B, T, D]
    const int*   __restrict__ wi,     // [B, S, W] word_indices
    const int*   __restrict__ wm,     // [B, S, W] word_mask
    const int*   __restrict__ wim,    // [B, S]    word_indices_mask
    const float* __restrict__ att_w,  // [D]
    const float* __restrict__ att_b,  // [1]
    float*       __restrict__ out)    // [B, S, D]
{
    const int bs   = blockIdx.x;          // 0 .. B*S-1
    const int b    = bs / NS;
    const int tid  = threadIdx.x;         // 0 .. 255
    const int lane = tid & 63;
    const int wave = tid >> 6;

    __shared__ float red[4][NW];

    // Uniform per-span metadata.
    const int* wip = wi + (size_t)bs * NW;
    const int* wmp = wm + (size_t)bs * NW;

    int   idx[NW];
    float mk[NW];
    #pragma unroll
    for (int w = 0; w < NW; ++w) {
        int v  = wip[w];
        idx[w] = v > 0 ? v : 0;           // relu clamp, matches reference
        mk[w]  = (float)wmp[w];
    }

    const float4 w4   = *reinterpret_cast<const float4*>(att_w + tid * 4);
    const float  bias = att_b[0];

    const float* tb = text + (size_t)b * NT * ND + tid * 4;

    // Gather 16 row fragments into registers; compute partial logits.
    float4 row[NW];
    float  p[NW];
    #pragma unroll
    for (int w = 0; w < NW; ++w) {
        row[w] = *reinterpret_cast<const float4*>(tb + (size_t)idx[w] * ND);
        p[w]   = row[w].x * w4.x + row[w].y * w4.y
               + row[w].z * w4.z + row[w].w * w4.w;
    }

    // 64-lane butterfly reduce each of the 16 partials.
    #pragma unroll
    for (int w = 0; w < NW; ++w) {
        float v = p[w];
        v += __shfl_xor(v, 1);
        v += __shfl_xor(v, 2);
        v += __shfl_xor(v, 4);
        v += __shfl_xor(v, 8);
        v += __shfl_xor(v, 16);
        v += __shfl_xor(v, 32);
        p[w] = v;
    }
    if (lane < NW) red[wave][lane] = p[lane];
    __syncthreads();

    // Every thread reconstructs the 16 full logits (broadcast LDS reads).
    float logit[NW];
    #pragma unroll
    for (int w = 0; w < NW; ++w)
        logit[w] = red[0][w] + red[1][w] + red[2][w] + red[3][w] + bias;

    // Masked softmax over W, replicating reference -1e9 + post-mask semantics.
    float ml[NW];
    float m = -3.0e38f;
    #pragma unroll
    for (int w = 0; w < NW; ++w) {
        ml[w] = (mk[w] != 0.0f) ? logit[w] : -1.0e9f;
        m = fmaxf(m, ml[w]);
    }
    float e[NW];
    float sum = 0.0f;
    #pragma unroll
    for (int w = 0; w < NW; ++w) {
        e[w] = expf(ml[w] - m);
        sum += e[w];
    }
    const float inv = 1.0f / sum;

    // Weighted-sum pooling over the register-resident row fragments.
    float4 acc = make_float4(0.f, 0.f, 0.f, 0.f);
    #pragma unroll
    for (int w = 0; w < NW; ++w) {
        const float wgt = e[w] * inv * mk[w];
        acc.x += wgt * row[w].x;
        acc.y += wgt * row[w].y;
        acc.z += wgt * row[w].z;
        acc.w += wgt * row[w].w;
    }

    const float sm = (float)wim[bs];
    acc.x *= sm; acc.y *= sm; acc.z *= sm; acc.w *= sm;

    *reinterpret_cast<float4*>(out + (size_t)bs * ND + tid * 4) = acc;
}

extern "C" void kernel_launch(void* const* d_in, const int* in_sizes, int n_in,
                              void* d_out, int out_size, void* d_ws, size_t ws_size,
                              hipStream_t stream) {
    const float* text  = (const float*)d_in[0];
    // d_in[1] = contextualized_embedding: unused by the reference.
    const int*   wi    = (const int*)d_in[2];
    const int*   wm    = (const int*)d_in[3];
    const int*   wim   = (const int*)d_in[4];
    const float* att_w = (const float*)d_in[5];
    const float* att_b = (const float*)d_in[6];
    float*       out   = (float*)d_out;

    dim3 grid(NB * NS);
    dim3 block(256);
    span_attn_kernel<<<grid, block, 0, stream>>>(text, wi, wm, wim, att_w, att_b, out);
}

// Round 3
// 32.478 us; speedup vs baseline: 1.2761x; 1.2761x over previous
//
#include <hip/hip_runtime.h>

#define NB 8
#define NT 2048
#define ND 1024
#define NS 512
#define NW 16

typedef float f32x4 __attribute__((ext_vector_type(4)));

// One block per (b, s) span. 256 threads; thread t owns d = 4t .. 4t+3.
// XCD swizzle: blocks are issued round-robin across the 8 XCDs, so decoding
// b = blockIdx & 7 pins all 512 spans of batch b to one XCD -> its gathers
// touch only text[b] (8 MB) instead of all of text (64 MB), 2x the 4 MB L2.
__global__ __launch_bounds__(256) void span_attn_kernel(
    const float* __restrict__ text,   // [B, T, D]
    const int*   __restrict__ wi,     // [B, S, W] word_indices
    const int*   __restrict__ wm,     // [B, S, W] word_mask
    const int*   __restrict__ wim,    // [B, S]    word_indices_mask
    const float* __restrict__ att_w,  // [D]
    const float* __restrict__ att_b,  // [1]
    float*       __restrict__ out)    // [B, S, D]
{
    const int b    = blockIdx.x & (NB - 1);   // XCD-aligned batch
    const int s    = blockIdx.x >> 3;
    const int bs   = b * NS + s;
    const int tid  = threadIdx.x;             // 0 .. 255
    const int lane = tid & 63;
    const int wave = tid >> 6;

    __shared__ float red[4][NW];

    // Uniform per-span metadata.
    const int* wip = wi + (size_t)bs * NW;
    const int* wmp = wm + (size_t)bs * NW;

    int   idx[NW];
    float mk[NW];
    #pragma unroll
    for (int w = 0; w < NW; ++w) {
        int v  = wip[w];
        idx[w] = v > 0 ? v : 0;               // relu clamp, matches reference
        mk[w]  = (float)wmp[w];
    }

    const float4 w4   = *reinterpret_cast<const float4*>(att_w + tid * 4);
    const float  bias = att_b[0];

    const float* tb = text + (size_t)b * NT * ND + tid * 4;

    // Gather 16 row fragments into registers; compute partial logits.
    float4 row[NW];
    float  p[NW];
    #pragma unroll
    for (int w = 0; w < NW; ++w) {
        row[w] = *reinterpret_cast<const float4*>(tb + (size_t)idx[w] * ND);
        p[w]   = row[w].x * w4.x + row[w].y * w4.y
               + row[w].z * w4.z + row[w].w * w4.w;
    }

    // 64-lane butterfly reduce each of the 16 partials.
    #pragma unroll
    for (int w = 0; w < NW; ++w) {
        float v = p[w];
        v += __shfl_xor(v, 1);
        v += __shfl_xor(v, 2);
        v += __shfl_xor(v, 4);
        v += __shfl_xor(v, 8);
        v += __shfl_xor(v, 16);
        v += __shfl_xor(v, 32);
        p[w] = v;
    }
    if (lane < NW) red[wave][lane] = p[lane];
    __syncthreads();

    // Every thread reconstructs the 16 full logits (broadcast LDS reads).
    float logit[NW];
    #pragma unroll
    for (int w = 0; w < NW; ++w)
        logit[w] = red[0][w] + red[1][w] + red[2][w] + red[3][w] + bias;

    // Masked softmax over W, replicating reference -1e9 + post-mask semantics.
    float ml[NW];
    float m = -3.0e38f;
    #pragma unroll
    for (int w = 0; w < NW; ++w) {
        ml[w] = (mk[w] != 0.0f) ? logit[w] : -1.0e9f;
        m = fmaxf(m, ml[w]);
    }
    float e[NW];
    float sum = 0.0f;
    #pragma unroll
    for (int w = 0; w < NW; ++w) {
        e[w] = expf(ml[w] - m);
        sum += e[w];
    }
    const float inv = 1.0f / sum;

    // Weighted-sum pooling over the register-resident row fragments.
    float4 acc = make_float4(0.f, 0.f, 0.f, 0.f);
    #pragma unroll
    for (int w = 0; w < NW; ++w) {
        const float wgt = e[w] * inv * mk[w];
        acc.x += wgt * row[w].x;
        acc.y += wgt * row[w].y;
        acc.z += wgt * row[w].z;
        acc.w += wgt * row[w].w;
    }

    const float sm = (float)wim[bs];
    acc.x *= sm; acc.y *= sm; acc.z *= sm; acc.w *= sm;

    // Non-temporal store: don't let the 16 MB output evict text from L2.
    // (native ext_vector type: __builtin_nontemporal_store rejects HIP float4)
    f32x4 accv;
    accv.x = acc.x; accv.y = acc.y; accv.z = acc.z; accv.w = acc.w;
    __builtin_nontemporal_store(accv,
        reinterpret_cast<f32x4*>(out + (size_t)bs * ND + tid * 4));
}

extern "C" void kernel_launch(void* const* d_in, const int* in_sizes, int n_in,
                              void* d_out, int out_size, void* d_ws, size_t ws_size,
                              hipStream_t stream) {
    const float* text  = (const float*)d_in[0];
    // d_in[1] = contextualized_embedding: unused by the reference.
    const int*   wi    = (const int*)d_in[2];
    const int*   wm    = (const int*)d_in[3];
    const int*   wim   = (const int*)d_in[4];
    const float* att_w = (const float*)d_in[5];
    const float* att_b = (const float*)d_in[6];
    float*       out   = (float*)d_out;

    dim3 grid(NB * NS);
    dim3 block(256);
    span_attn_kernel<<<grid, block, 0, stream>>>(text, wi, wm, wim, att_w, att_b, out);
}